// Round 1
// 1463.759 us; speedup vs baseline: 1.3660x; 1.3660x over previous
//
#include <hip/hip_runtime.h>
#include <hip/hip_bf16.h>

using bf16 = __hip_bfloat16;
using bf16x2 = __hip_bfloat162;
typedef __attribute__((ext_vector_type(8))) short short8;
typedef __attribute__((ext_vector_type(4))) float f32x4;

__device__ __forceinline__ float b2f(bf16 v) { return __bfloat162float(v); }
__device__ __forceinline__ bf16 f2b(float v) { return __float2bfloat16(v); }

// async global->LDS, 16B per lane; dest must be wave-uniform base + lane*16
__device__ __forceinline__ void gload_lds16(const bf16* g, bf16* l)
{
    __builtin_amdgcn_global_load_lds(
        (const __attribute__((address_space(1))) void*)g,
        (__attribute__((address_space(3))) void*)l,
        16, 0, 0);
}

// ---------------- NCHW f32 -> NHWC bf16 transpose (optionally halo-padded out) ----------------
__global__ __launch_bounds__(256) void nchw_to_nhwc(const float* __restrict__ in,
                                                    bf16* __restrict__ out,
                                                    int C, int H, int W, int pad)
{
    __shared__ bf16 tile[64][68];
    const int S = H * W;
    const int HP = H + 2 * pad, WP = W + 2 * pad;
    const int b = blockIdx.x, s0 = blockIdx.y * 64, c0 = blockIdx.z * 64;
    const int t = threadIdx.x;
    const int a = t & 63, q = t >> 6;
#pragma unroll
    for (int i = 0; i < 16; ++i) {
        int cl = q + i * 4;
        int s = s0 + a;
        tile[cl][a] = (s < S) ? f2b(in[((size_t)b * C + c0 + cl) * S + s]) : f2b(0.f);
    }
    __syncthreads();
#pragma unroll
    for (int i = 0; i < 16; ++i) {
        int sl = q + i * 4;
        int s = s0 + sl;
        if (s < S) {
            int y = s / W, x = s - (s / W) * W;
            out[(((size_t)b * HP + y + pad) * WP + x + pad) * C + c0 + a] = tile[a][sl];
        }
    }
}

// ---------------- zero the 1-px halo of a padded NHWC buffer ----------------
__global__ __launch_bounds__(256) void halo_zero(bf16* __restrict__ buf, int W, int C)
{
    const int b = blockIdx.x, y = blockIdx.y;
    const int P = W + 2;
    const bf16 z = f2b(0.f);
    bf16* row = buf + ((size_t)b * P + y) * P * C;
    if (y == 0 || y == P - 1) {
        for (int i = threadIdx.x; i < P * C; i += 256) row[i] = z;
    } else {
        for (int i = threadIdx.x; i < 2 * C; i += 256) {
            const int x = (i < C) ? 0 : P - 1;
            const int c = (i < C) ? i : i - C;
            row[(size_t)x * C + c] = z;
        }
    }
}

// ---------------- pack NHWC bf16 halves -> NCHW f32 concat output ----------------
__global__ __launch_bounds__(256) void pack_out(const bf16* __restrict__ x1o,
                                                const bf16* __restrict__ x2o,
                                                float* __restrict__ out)
{
    __shared__ bf16 tile[64][68];
    const int b = blockIdx.x, s0 = blockIdx.y * 64, ch0 = blockIdx.z * 64;
    const bf16* src = (ch0 < 512) ? x1o : x2o;
    const int c0 = ch0 & 511;
    const int t = threadIdx.x;
    const int a = t & 63, q = t >> 6;
#pragma unroll
    for (int i = 0; i < 16; ++i) {
        int sl = q + i * 4;
        tile[sl][a] = src[((size_t)b * 1600 + s0 + sl) * 512 + c0 + a];
    }
    __syncthreads();
#pragma unroll
    for (int i = 0; i < 16; ++i) {
        int cl = q + i * 4;
        out[((size_t)b * 1024 + ch0 + cl) * 1600 + s0 + a] = b2f(tile[a][cl]);
    }
}

// ------- weight reorder+convert: w[o][c][ky][kx] f32 -> wr[o][(ky*3+kx)*C + c] bf16 -------
__global__ __launch_bounds__(256) void reorder_w(const float* __restrict__ w,
                                                 bf16* __restrict__ wr,
                                                 int C, int total)
{
    int i = blockIdx.x * 256 + threadIdx.x;
    if (i >= total) return;
    int nineC = 9 * C;
    int o = i / nineC;
    int r = i - o * nineC;
    int tap = r / C;
    int c = r - tap * C;
    wr[i] = f2b(w[((size_t)o * C + c) * 9 + tap]);
}

// ---------------- plain f32 -> bf16 convert ----------------
__global__ __launch_bounds__(256) void f32_to_bf16(const float* __restrict__ in,
                                                   bf16* __restrict__ out, int n)
{
    int i = blockIdx.x * 256 + threadIdx.x;
    if (i < n) out[i] = f2b(in[i]);
}

// ---------------- patch mean pool: x2 NHWC -> kp[b*100][512] bf16 ----------------
__global__ __launch_bounds__(256) void pool_kp(const bf16* __restrict__ x2n,
                                               bf16* __restrict__ kp)
{
    const int p = blockIdx.x;            // b*100 + l
    const int b = p / 100, l = p - (p / 100) * 100;
    const int ph = l / 10, pw = l - (l / 10) * 10;
    const int t = threadIdx.x;           // 256 threads, 2 channels each
    const bf16x2* base = (const bf16x2*)(x2n + (((size_t)(b * 40 + ph * 4) * 40) + pw * 4) * 512) + t;
    float sx = 0.f, sy = 0.f;
#pragma unroll
    for (int py = 0; py < 4; ++py)
#pragma unroll
        for (int px = 0; px < 4; ++px) {
            float2 v = __bfloat1622float2(base[(py * 40 + px) * 256]);
            sx += v.x; sy += v.y;
        }
    ((bf16x2*)(kp + (size_t)p * 512))[t] = __float22bfloat162_rn(make_float2(sx * 0.0625f, sy * 0.0625f));
}

// ---------------- channel-attention MLP at 20x20 source resolution ----------------
// reads halo-padded x1n (22x22), writes halo-padded xca (42x42)
__global__ __launch_bounds__(256) void ca_mlp(const bf16* __restrict__ x1n,
                                              const float* __restrict__ w1, const float* __restrict__ b1,
                                              const float* __restrict__ w2, const float* __restrict__ b2,
                                              bf16* __restrict__ xca)
{
    __shared__ float a1v[256];
    __shared__ float part[4][64];
    __shared__ float hid[64];
    const int blk = blockIdx.x;
    const int b = blk / 400;
    const int rem = blk - b * 400;
    const int y = rem / 20, x = rem - (rem / 20) * 20;
    const int t = threadIdx.x;
    const bf16* src = x1n + ((size_t)(b * 22 + y + 1) * 22 + x + 1) * 512 + 256;
    a1v[t] = b2f(src[t]);
    __syncthreads();
    {
        const int h = t & 63, seg = t >> 6;
        float acc = 0.f;
        const float* wp = w1 + (size_t)h * 256 + seg * 64;
        const float* ap = a1v + seg * 64;
#pragma unroll 8
        for (int c = 0; c < 64; ++c) acc += wp[c] * ap[c];
        part[seg][h] = acc;
    }
    __syncthreads();
    if (t < 64)
        hid[t] = fmaxf(part[0][t] + part[1][t] + part[2][t] + part[3][t] + b1[t], 0.f);
    __syncthreads();
    float acc2 = b2[t];
    const float* w2p = w2 + (size_t)t * 64;
#pragma unroll 8
    for (int h = 0; h < 64; ++h) acc2 += w2p[h] * hid[h];
    const float g = 1.f / (1.f + __expf(-acc2));
    const bf16 o = f2b(a1v[t] * g);
    const size_t obase = ((size_t)(b * 42 + 2 * y + 1) * 42 + 2 * x + 1) * 256 + t;
    xca[obase] = o;
    xca[obase + 256] = o;
    xca[obase + 42 * 256] = o;
    xca[obase + 42 * 256 + 256] = o;
}

// ---------------- attention: one block per (batch,head) ----------------
__global__ __launch_bounds__(256, 1)
void attn_kernel(const float* __restrict__ q, const float* __restrict__ k,
                 const bf16* __restrict__ x2n, bf16* __restrict__ attn)
{
    __shared__ float sc[100][100];
    __shared__ bf16 wT[100][104];   // wT[l][ql]
    const int t = threadIdx.x;
    const int n = blockIdx.x;
    const int b = n >> 3, hd = n & 7;
    const float* qn = q + (size_t)n * 3200;
    const float* kn = k + (size_t)n * 3200;
    for (int e = t; e < 10000; e += 256) {
        const int i = e / 100;
        const int j = e - i * 100;
        const float4* qa = (const float4*)(qn + i * 32);
        const float4* ka = (const float4*)(kn + j * 32);
        float d = 0.f;
#pragma unroll
        for (int u = 0; u < 8; ++u) {
            float4 xv = qa[u], yv = ka[u];
            d += xv.x * yv.x + xv.y * yv.y + xv.z * yv.z + xv.w * yv.w;
        }
        sc[i][j] = d * 0.17677669529663687f;   // 1/sqrt(32)
    }
    __syncthreads();
    if (t < 100) {
        float mx = -1e30f;
        for (int j = 0; j < 100; ++j) mx = fmaxf(mx, sc[t][j]);
        float s = 0.f;
        for (int j = 0; j < 100; ++j) s += __expf(sc[t][j] - mx);
        const float inv = 1.f / s;
        for (int j = 0; j < 100; ++j) wT[j][t] = f2b(__expf(sc[t][j] - mx) * inv);
    }
    __syncthreads();
    const int ch0 = (t & 15) * 4;
    const int pix = t >> 4;
    const int py = pix >> 2, px = pix & 3;
    const bf16* vbase = x2n + (((size_t)(b * 40 + py) * 40) + px) * 512 + hd * 64 + ch0;
    for (int ql0 = 0; ql0 < 100; ql0 += 20) {
        float2 a0[20], a1[20];
#pragma unroll
        for (int i = 0; i < 20; ++i) { a0[i] = make_float2(0.f, 0.f); a1[i] = make_float2(0.f, 0.f); }
        for (int l = 0; l < 100; ++l) {
            const int ph = l / 10, pw = l - (l / 10) * 10;
            const bf16* vp = vbase + ((size_t)(ph * 160 + pw * 4)) * 512;
            const float2 v01 = __bfloat1622float2(*(const bf16x2*)vp);
            const float2 v23 = __bfloat1622float2(*(const bf16x2*)(vp + 2));
            const bf16x2* wp = (const bf16x2*)&wT[l][ql0];
#pragma unroll
            for (int ii = 0; ii < 10; ++ii) {
                const float2 w2 = __bfloat1622float2(wp[ii]);
                a0[ii * 2 + 0].x += w2.x * v01.x; a0[ii * 2 + 0].y += w2.x * v01.y;
                a1[ii * 2 + 0].x += w2.x * v23.x; a1[ii * 2 + 0].y += w2.x * v23.y;
                a0[ii * 2 + 1].x += w2.y * v01.x; a0[ii * 2 + 1].y += w2.y * v01.y;
                a1[ii * 2 + 1].x += w2.y * v23.x; a1[ii * 2 + 1].y += w2.y * v23.y;
            }
        }
#pragma unroll
        for (int i = 0; i < 20; ++i) {
            const int ql = ql0 + i;
            const int ph = ql / 10, pw = ql - (ql / 10) * 10;
            // halo-padded 42x42 output
            bf16* op = attn + (((size_t)(b * 42 + ph * 4 + py + 1) * 42) + pw * 4 + px + 1) * 512 + hd * 64 + ch0;
            *(bf16x2*)op = __float22bfloat162_rn(a0[i]);
            *(bf16x2*)(op + 2) = __float22bfloat162_rn(a1[i]);
        }
    }
}

// ---------------- generic implicit-GEMM MFMA conv (gload_lds + XOR-swizzled LDS) ----------------
enum ConvMode { M_QCONV = 0, M_SA1 = 1, M_SA2 = 2, M_C3 = 3, M_CONV2 = 4, M_KPROJ = 5 };

template <int MODE>
__global__ __launch_bounds__(256, 2)
void conv_mfma(const bf16* __restrict__ in, const bf16* __restrict__ in2,
               const bf16* __restrict__ wr,
               const float* __restrict__ scale, const float* __restrict__ bias,
               const bf16* __restrict__ resid,
               bf16* __restrict__ outb, float* __restrict__ outf)
{
    constexpr int CIN  = (MODE == M_QCONV || MODE == M_C3 || MODE == M_KPROJ) ? 512
                       : (MODE == M_CONV2 ? 768 : 256);
    constexpr int TAPS = (MODE == M_CONV2 || MODE == M_KPROJ) ? 1 : 9;
    constexpr int SP   = (MODE == M_QCONV || MODE == M_KPROJ) ? 100 : 1600;
    constexpr int STR  = (MODE == M_QCONV) ? 2 : 1;
    constexpr int HP   = (MODE == M_QCONV) ? 22 : 42;   // halo-padded input dim
    constexpr int WOUT = (MODE == M_QCONV || MODE == M_KPROJ) ? 10 : 40;
    constexpr int K    = TAPS * CIN;
    constexpr int KD   = (TAPS == 9) ? 3 : 1;

    __shared__ bf16 Al[128][64];
    __shared__ bf16 Bl[128][64];

    const int t = threadIdx.x;
    const int p0 = blockIdx.x * 128;
    const int n0 = blockIdx.y * 128;

    int s_row[4], s_dst8[4], s_src8[4], s_b[4], s_oy[4], s_ox[4];
    const bf16* bB[4];
#pragma unroll
    for (int i = 0; i < 4; ++i) {
        const int task = t + i * 256;
        const int row = task >> 3, chk = task & 7;
        s_row[i] = row;
        s_dst8[i] = chk * 8;                    // linear LDS dest chunk
        s_src8[i] = (chk ^ (row & 7)) * 8;      // pre-swizzled global source chunk
        const int p = p0 + row;
        const int bb = p / SP;
        const int s = p - bb * SP;
        s_b[i] = bb;
        s_oy[i] = s / WOUT;
        s_ox[i] = s - s_oy[i] * WOUT;
        bB[i] = wr + (size_t)(n0 + row) * K + s_src8[i];
    }

    const bf16* aP1[4];
    const bf16* aP2[4];
    if (MODE == M_CONV2) {
#pragma unroll
        for (int i = 0; i < 4; ++i) {
            aP1[i] = in + ((size_t)(s_b[i] * 22 + (s_oy[i] >> 1) + 1) * 22 + (s_ox[i] >> 1) + 1) * 512 + s_src8[i];
            aP2[i] = in2 + ((size_t)(s_b[i] * 1600 + s_oy[i] * 40 + s_ox[i])) * 256 + s_src8[i];
        }
    }
    if (MODE == M_KPROJ) {
#pragma unroll
        for (int i = 0; i < 4; ++i)
            aP1[i] = in + (size_t)(p0 + s_row[i]) * 512 + s_src8[i];
    }

    const int lane = t & 63;
    const int wv = t >> 6;
    const int m_off = (wv >> 1) * 64;
    const int n_off = (wv & 1) * 64;
    const int fr = lane & 15;
    const int qd = lane >> 4;
    const int xa = (fr & 7) << 4;   // read-side XOR (row&7)<<4; fragment rows have row&7 == fr&7

    f32x4 acc[4][4];
#pragma unroll
    for (int mi = 0; mi < 4; ++mi)
#pragma unroll
        for (int ni = 0; ni < 4; ++ni)
            acc[mi][ni] = (f32x4){0.f, 0.f, 0.f, 0.f};

    for (int ky = 0; ky < KD; ++ky)
    for (int kx = 0; kx < KD; ++kx) {
        const bf16* aT[4];
        if (TAPS == 9) {
#pragma unroll
            for (int i = 0; i < 4; ++i)
                aT[i] = in + ((size_t)((s_b[i] * HP + s_oy[i] * STR + ky) * HP) + s_ox[i] * STR + kx) * CIN + s_src8[i];
        }
        const int kk0 = (ky * KD + kx) * CIN;
        for (int c0 = 0; c0 < CIN; c0 += 64) {
            // ---- async stage A ----
#pragma unroll
            for (int i = 0; i < 4; ++i) {
                const bf16* sa;
                if (MODE == M_CONV2)      sa = (c0 < 512) ? (aP1[i] + c0) : (aP2[i] + (c0 - 512));
                else if (MODE == M_KPROJ) sa = aP1[i] + c0;
                else                      sa = aT[i] + c0;
                gload_lds16(sa, &Al[s_row[i]][s_dst8[i]]);
            }
            // ---- async stage B ----
#pragma unroll
            for (int i = 0; i < 4; ++i)
                gload_lds16(bB[i] + (kk0 + c0), &Bl[s_row[i]][s_dst8[i]]);
            __syncthreads();   // compiler drains vmcnt before s_barrier
            // ---- MFMA phase, swizzled ds_read_b128 ----
#pragma unroll
            for (int ks = 0; ks < 2; ++ks) {
                short8 af[4], bfr[4];
                const int coff = (ks * 64 + qd * 16) ^ xa;
#pragma unroll
                for (int mi = 0; mi < 4; ++mi)
                    af[mi] = *(const short8*)((const char*)&Al[m_off + mi * 16 + fr][0] + coff);
#pragma unroll
                for (int ni = 0; ni < 4; ++ni)
                    bfr[ni] = *(const short8*)((const char*)&Bl[n_off + ni * 16 + fr][0] + coff);
#pragma unroll
                for (int mi = 0; mi < 4; ++mi)
#pragma unroll
                    for (int ni = 0; ni < 4; ++ni)
                        acc[mi][ni] = __builtin_amdgcn_mfma_f32_16x16x32_bf16(af[mi], bfr[ni], acc[mi][ni], 0, 0, 0);
            }
            __syncthreads();
        }
    }

    // ---- epilogue ----
#pragma unroll
    for (int ni = 0; ni < 4; ++ni) {
        const int nn = n0 + n_off + ni * 16 + fr;
        float scv = 1.f, bsv = 0.f;
        if (MODE != M_KPROJ) { scv = scale[nn]; bsv = bias[nn]; }
#pragma unroll
        for (int mi = 0; mi < 4; ++mi) {
            const int mb = p0 + m_off + mi * 16 + qd * 4;
#pragma unroll
            for (int r = 0; r < 4; ++r) {
                const int p = mb + r;
                const float v = acc[mi][ni][r];
                if (MODE == M_KPROJ) {
                    const int bb = p / 100, l = p - (p / 100) * 100;
                    outf[(((size_t)(bb * 8 + (nn >> 5))) * 100 + l) * 32 + (nn & 31)] = v;
                } else {
                    const float y = v * scv + bsv;
                    const float a = y / (1.f + __expf(-y));
                    if (MODE == M_QCONV) {
                        const int bb = p / 100, l = p - (p / 100) * 100;
                        outf[(((size_t)(bb * 8 + (nn >> 5))) * 100 + l) * 32 + (nn & 31)] = a;
                    } else if (MODE == M_SA1) {
                        const int bb = p / 1600; const int s = p - bb * 1600;
                        const int oy = s / 40, ox = s - (s / 40) * 40;
                        outb[(((size_t)(bb * 42 + oy + 1)) * 42 + ox + 1) * 256 + nn] = f2b(a);
                    } else if (MODE == M_SA2) {
                        const int bb = p / 1600; const int s = p - bb * 1600;
                        const int oy = s / 40, ox = s - (s / 40) * 40;
                        const size_t roff = (((size_t)(bb * 42 + oy + 1)) * 42 + ox + 1) * 256 + nn;
                        outb[(size_t)p * 256 + nn] = f2b(a + b2f(resid[roff]));
                    } else if (MODE == M_C3) {
                        const int bb = p / 1600; const int s = p - bb * 1600;
                        const int oy = s / 40, ox = s - (s / 40) * 40;
                        const size_t roff = (((size_t)(bb * 42 + oy + 1)) * 42 + ox + 1) * 512 + nn;
                        outb[(size_t)p * 512 + nn] = f2b(a + b2f(resid[roff]));
                    } else { // M_CONV2
                        outb[(size_t)p * 512 + nn] = f2b(a);
                    }
                }
            }
        }
    }
}

extern "C" void kernel_launch(void* const* d_in, const int* in_sizes, int n_in,
                              void* d_out, int out_size, void* d_ws, size_t ws_size,
                              hipStream_t stream)
{
    const float* x1      = (const float*)d_in[0];
    const float* x2      = (const float*)d_in[1];
    const float* q_w     = (const float*)d_in[2];
    const float* q_s     = (const float*)d_in[3];
    const float* q_b     = (const float*)d_in[4];
    const float* key_w   = (const float*)d_in[5];
    const float* ca_w1   = (const float*)d_in[6];
    const float* ca_b1   = (const float*)d_in[7];
    const float* ca_w2   = (const float*)d_in[8];
    const float* ca_b2   = (const float*)d_in[9];
    const float* sa1_w   = (const float*)d_in[10];
    const float* sa1_s   = (const float*)d_in[11];
    const float* sa1_b   = (const float*)d_in[12];
    const float* sa2_w   = (const float*)d_in[13];
    const float* sa2_s   = (const float*)d_in[14];
    const float* sa2_b   = (const float*)d_in[15];
    const float* conv2_w = (const float*)d_in[16];
    const float* conv2_s = (const float*)d_in[17];
    const float* conv2_b = (const float*)d_in[18];
    const float* c3_w    = (const float*)d_in[19];
    const float* c3_s    = (const float*)d_in[20];
    const float* c3_b    = (const float*)d_in[21];

    char* ws = (char*)d_ws;
    // workspace layout (bytes) — padded NHWC buffers, aggressive aliasing; peak 213,254,144
    const size_t o_x1n  = 0;                 // 32*22*22*512 bf16 : 15,859,712 (halo)
    const size_t o_x2n  = 15859712;          // 32*1600*512 bf16  : 52,428,800 (x2o alias after attn)
    const size_t o_attn = 68288512;          // 32*42*42*512 bf16 : 57,802,752 (halo; x1o alias after C3)
    const size_t o_xca  = 126091264;         // 32*42*42*256 bf16 : 28,901,376 (halo; wc3 alias after SA2)
    const size_t o_tbuf = 154992640;         // 32*42*42*256 bf16 : 28,901,376 (halo; k/q/wkey alias before SA1)
    const size_t o_a2   = 183894016;         // 32*1600*256 bf16  : 26,214,400 (kp/wq alias before SA2)
    const size_t o_ws1  = 210108416;         // 256*2304 bf16 : 1,179,648
    const size_t o_ws2  = 211288064;         // 256*2304 bf16 : 1,179,648
    const size_t o_wc2  = 212467712;         // 512*768  bf16 :   786,432
    // aliases
    const size_t o_k    = o_tbuf;            // 3,276,800 f32
    const size_t o_q    = o_tbuf + 3276800;  // 3,276,800 f32
    const size_t o_wkey = o_tbuf + 6553600;  //   262,144 bf16
    const size_t o_kp   = o_a2;              // 3,276,800 bf16
    const size_t o_wq   = o_a2 + 3276800;    // 2,359,296 bf16
    const size_t o_wc3  = o_xca;             // 4,718,592 bf16

    bf16*  x1n    = (bf16*)(ws + o_x1n);
    bf16*  x2n    = (bf16*)(ws + o_x2n);
    float* k_attn = (float*)(ws + o_k);
    float* q_attn = (float*)(ws + o_q);
    bf16*  attn   = (bf16*)(ws + o_attn);
    bf16*  xca    = (bf16*)(ws + o_xca);
    bf16*  tbuf   = (bf16*)(ws + o_tbuf);
    bf16*  a2     = (bf16*)(ws + o_a2);
    bf16*  wq     = (bf16*)(ws + o_wq);
    bf16*  wc3    = (bf16*)(ws + o_wc3);
    bf16*  wsa1   = (bf16*)(ws + o_ws1);
    bf16*  wsa2   = (bf16*)(ws + o_ws2);
    bf16*  kp     = (bf16*)(ws + o_kp);
    bf16*  wkey   = (bf16*)(ws + o_wkey);
    bf16*  wc2    = (bf16*)(ws + o_wc2);
    bf16*  x2o    = (bf16*)(ws + o_x2n);     // alias: x2n dead after attn_kernel
    bf16*  x1o    = (bf16*)(ws + o_attn);    // alias: attn dead after C3

    const dim3 blk(256);

    // halos (disjoint from interior writes); tbuf halo must wait (region hosts k/q/wkey)
    halo_zero<<<dim3(32, 22), blk, 0, stream>>>(x1n, 20, 512);
    halo_zero<<<dim3(32, 42), blk, 0, stream>>>(xca, 40, 256);
    halo_zero<<<dim3(32, 42), blk, 0, stream>>>(attn, 40, 512);

    nchw_to_nhwc<<<dim3(32, 7, 8), blk, 0, stream>>>(x1, x1n, 512, 20, 20, 1);
    nchw_to_nhwc<<<dim3(32, 25, 8), blk, 0, stream>>>(x2, x2n, 512, 40, 40, 0);
    reorder_w<<<4608, blk, 0, stream>>>(q_w,  wq,   512, 256 * 512 * 9);
    reorder_w<<<2304, blk, 0, stream>>>(sa1_w, wsa1, 256, 256 * 256 * 9);
    reorder_w<<<2304, blk, 0, stream>>>(sa2_w, wsa2, 256, 256 * 256 * 9);
    f32_to_bf16<<<512, blk, 0, stream>>>(key_w, wkey, 256 * 512);
    f32_to_bf16<<<1536, blk, 0, stream>>>(conv2_w, wc2, 512 * 768);
    pool_kp<<<3200, blk, 0, stream>>>(x2n, kp);

    conv_mfma<M_KPROJ><<<dim3(25, 2), blk, 0, stream>>>(kp, nullptr, wkey,
        nullptr, nullptr, nullptr, nullptr, k_attn);
    conv_mfma<M_QCONV><<<dim3(25, 2), blk, 0, stream>>>(x1n, nullptr, wq,
        q_s, q_b, nullptr, nullptr, q_attn);

    attn_kernel<<<256, blk, 0, stream>>>(q_attn, k_attn, x2n, attn);

    // k/q/wkey dead now; zero tbuf halo before SA1/SA2 use it
    halo_zero<<<dim3(32, 42), blk, 0, stream>>>(tbuf, 40, 256);

    ca_mlp<<<12800, blk, 0, stream>>>(x1n, ca_w1, ca_b1, ca_w2, ca_b2, xca);

    conv_mfma<M_SA1><<<dim3(400, 2), blk, 0, stream>>>(xca, nullptr, wsa1,
        sa1_s, sa1_b, nullptr, tbuf, nullptr);
    conv_mfma<M_SA2><<<dim3(400, 2), blk, 0, stream>>>(tbuf, nullptr, wsa2,
        sa2_s, sa2_b, xca, a2, nullptr);

    // xca dead; build wc3 in its slot just before C3
    reorder_w<<<9216, blk, 0, stream>>>(c3_w, wc3, 512, 512 * 512 * 9);
    conv_mfma<M_C3><<<dim3(400, 4), blk, 0, stream>>>(attn, nullptr, wc3,
        c3_s, c3_b, attn, x2o, nullptr);
    conv_mfma<M_CONV2><<<dim3(400, 4), blk, 0, stream>>>(x1n, a2, wc2,
        conv2_s, conv2_b, nullptr, x1o, nullptr);

    pack_out<<<dim3(32, 25, 16), blk, 0, stream>>>(x1o, x2o, (float*)d_out);

    (void)in_sizes; (void)n_in; (void)out_size; (void)ws_size;
}